// Round 1
// baseline (586.112 us; speedup 1.0000x reference)
//
#include <hip/hip_runtime.h>

#define D 64
#define LN_EPS 1e-5f

// Phase 1: edge scatter. One lane per (edge, feature). Lane d of the edge's
// 64-lane group reads x[src][d] (coalesced 256B/wave) and atomicAdd's into
// agg[dst][d] (coalesced atomics, 2 cache lines per edge). Lane 0 bumps deg.
__global__ __launch_bounds__(256) void scatter_kernel(
    const int* __restrict__ ei, const float* __restrict__ x,
    float* __restrict__ agg, float* __restrict__ deg, int E)
{
    long long tid = (long long)blockIdx.x * 256 + threadIdx.x;
    long long total = (long long)E * D;
    if (tid >= total) return;
    int e    = (int)(tid >> 6);
    int lane = (int)(tid & 63);
    int dst = ei[e];        // row 0 = i (dst)
    int src = ei[E + e];    // row 1 = j (src)
    atomicAdd(&agg[(size_t)dst * D + lane], x[(size_t)src * D + lane]);
    if (lane == 0) atomicAdd(&deg[dst], 1.0f);
}

// Phase 2: one thread per node. W offsets are wave-uniform (k is a loop
// counter) -> compiler scalarizes W loads to s_load; inner body is v_fmac
// with SGPR operand. acc[64] lives in VGPRs (indices constant after unroll).
// Reads agg row fully before overwriting it in-place with the final output.
__global__ __launch_bounds__(256) void node_update_kernel(
    const float* __restrict__ x, const float* __restrict__ deg,
    const float* __restrict__ W, const float* __restrict__ b,
    const float* __restrict__ gamma, const float* __restrict__ beta,
    float* __restrict__ agg_out, int N)
{
    int n = blockIdx.x * 256 + threadIdx.x;
    if (n >= N) return;

    float acc[D];
    #pragma unroll
    for (int o = 0; o < D; ++o) acc[o] = b[o];

    const float* xr = x + (size_t)n * D;
    float* ar = agg_out + (size_t)n * D;
    float inv = 1.0f / fmaxf(deg[n], 1.0f);

    // h[0:64] = x[n]
    for (int k = 0; k < D; ++k) {
        float hx = xr[k];
        #pragma unroll
        for (int o = 0; o < D; ++o)
            acc[o] = fmaf(hx, W[o * 128 + k], acc[o]);
    }
    // h[64:128] = agg[n] / max(deg,1)
    for (int k = 0; k < D; ++k) {
        float ha = ar[k] * inv;
        #pragma unroll
        for (int o = 0; o < D; ++o)
            acc[o] = fmaf(ha, W[o * 128 + 64 + k], acc[o]);
    }

    // ReLU + LayerNorm (thread owns the whole row -> no cross-lane reduce)
    float mu = 0.f;
    #pragma unroll
    for (int o = 0; o < D; ++o) { acc[o] = fmaxf(acc[o], 0.f); mu += acc[o]; }
    mu *= (1.0f / D);
    float var = 0.f;
    #pragma unroll
    for (int o = 0; o < D; ++o) { float d0 = acc[o] - mu; var += d0 * d0; }
    var *= (1.0f / D);
    float r = rsqrtf(var + LN_EPS);
    #pragma unroll
    for (int o = 0; o < D; ++o)
        ar[o] = (acc[o] - mu) * r * gamma[o] + beta[o];
}

extern "C" void kernel_launch(void* const* d_in, const int* in_sizes, int n_in,
                              void* d_out, int out_size, void* d_ws, size_t ws_size,
                              hipStream_t stream)
{
    const float* x     = (const float*)d_in[0];
    const int*   ei    = (const int*)d_in[1];
    const float* W     = (const float*)d_in[2];
    const float* b     = (const float*)d_in[3];
    const float* gamma = (const float*)d_in[4];
    const float* beta  = (const float*)d_in[5];

    int N = in_sizes[0] / D;       // 100000
    int E = in_sizes[1] / 2;       // 1600000

    float* agg = (float*)d_out;    // reuse output buffer as agg scratch (N*64 floats)
    float* deg = (float*)d_ws;     // N floats

    hipMemsetAsync(agg, 0, (size_t)N * D * sizeof(float), stream);
    hipMemsetAsync(deg, 0, (size_t)N * sizeof(float), stream);

    long long total = (long long)E * D;
    int sblocks = (int)((total + 255) / 256);
    scatter_kernel<<<sblocks, 256, 0, stream>>>(ei, x, agg, deg, E);

    int nblocks = (N + 255) / 256;
    node_update_kernel<<<nblocks, 256, 0, stream>>>(x, deg, W, b, gamma, beta, agg, N);
}

// Round 2
// 413.764 us; speedup vs baseline: 1.4165x; 1.4165x over previous
//
#include <hip/hip_runtime.h>

#define D 64
#define LN_EPS 1e-5f

// ---------------- CSR build ----------------

__global__ __launch_bounds__(256) void hist_kernel(
    const int* __restrict__ ei, int* __restrict__ degi, int E)
{
    int e = blockIdx.x * 256 + threadIdx.x;
    if (e < E) atomicAdd(&degi[ei[e]], 1);
}

// per-block exclusive scan (Hillis-Steele in LDS), emits block sums
__global__ __launch_bounds__(256) void scan1_kernel(
    const int* __restrict__ degi, int* __restrict__ locExcl,
    int* __restrict__ bsum, int N)
{
    __shared__ int s[256];
    int tid = threadIdx.x;
    int i = blockIdx.x * 256 + tid;
    int v = (i < N) ? degi[i] : 0;
    s[tid] = v;
    __syncthreads();
    for (int off = 1; off < 256; off <<= 1) {
        int t = (tid >= off) ? s[tid - off] : 0;
        __syncthreads();
        s[tid] += t;
        __syncthreads();
    }
    if (i < N) locExcl[i] = s[tid] - v;
    if (tid == 255) bsum[blockIdx.x] = s[255];
}

// scan the (<=512) block sums in a single block
__global__ __launch_bounds__(512) void scan2_kernel(int* __restrict__ bsum, int nb)
{
    __shared__ int s[512];
    int tid = threadIdx.x;
    int v = (tid < nb) ? bsum[tid] : 0;
    s[tid] = v;
    __syncthreads();
    for (int off = 1; off < 512; off <<= 1) {
        int t = (tid >= off) ? s[tid - off] : 0;
        __syncthreads();
        s[tid] += t;
        __syncthreads();
    }
    if (tid < nb) bsum[tid] = s[tid] - v;   // exclusive
}

__global__ __launch_bounds__(256) void scan3_kernel(
    const int* __restrict__ locExcl, const int* __restrict__ bsum,
    int* __restrict__ offsets, int* __restrict__ cursor, int N)
{
    int i = blockIdx.x * 256 + threadIdx.x;
    if (i < N) {
        int o = locExcl[i] + bsum[blockIdx.x];
        offsets[i] = o;
        cursor[i]  = o;
    }
}

__global__ __launch_bounds__(256) void fill_kernel(
    const int* __restrict__ ei, int* __restrict__ cursor,
    int* __restrict__ col, int E)
{
    int e = blockIdx.x * 256 + threadIdx.x;
    if (e >= E) return;
    int dst = ei[e];
    int src = ei[E + e];
    int pos = atomicAdd(&cursor[dst], 1);
    col[pos] = src;
}

// W[64][128] row-major -> WT[128][64] so WT[k*64+o] = W[o*128+k]
__global__ __launch_bounds__(256) void wt_kernel(
    const float* __restrict__ W, float* __restrict__ WT)
{
    int t = blockIdx.x * 256 + threadIdx.x;   // 8192 total
    int k = t >> 6, o = t & 63;
    WT[t] = W[o * 128 + k];
}

// ---------------- gather aggregation: one wave per node ----------------
// lane d holds feature d; neighbor indices broadcast via __shfl; each
// neighbor is one fully-coalesced 256B row load (L2/L3-resident x).
__global__ __launch_bounds__(256) void gather_kernel(
    const int* __restrict__ col, const int* __restrict__ offsets,
    const int* __restrict__ degi, const float* __restrict__ x,
    float* __restrict__ out, int N)
{
    int w    = (blockIdx.x * 256 + threadIdx.x) >> 6;
    int lane = threadIdx.x & 63;
    if (w >= N) return;
    int base = offsets[w];
    int cnt  = degi[w];
    float sum = 0.f;
    for (int t = 0; t < cnt; t += 64) {
        int m = cnt - t; if (m > 64) m = 64;
        int idx = (lane < m) ? col[base + t + lane] : 0;
        int j = 0;
        for (; j + 4 <= m; j += 4) {      // 4 loads in flight
            int s0 = __shfl(idx, j);
            int s1 = __shfl(idx, j + 1);
            int s2 = __shfl(idx, j + 2);
            int s3 = __shfl(idx, j + 3);
            float v0 = x[(size_t)s0 * D + lane];
            float v1 = x[(size_t)s1 * D + lane];
            float v2 = x[(size_t)s2 * D + lane];
            float v3 = x[(size_t)s3 * D + lane];
            sum += v0; sum += v1; sum += v2; sum += v3;
        }
        for (; j < m; ++j) {
            int s0 = __shfl(idx, j);
            sum += x[(size_t)s0 * D + lane];
        }
    }
    float inv = 1.0f / fmaxf((float)cnt, 1.0f);
    out[(size_t)w * D + lane] = sum * inv;    // store the mean directly
}

// ---------------- fused linear + ReLU + LayerNorm ----------------
// Thread-per-node. WT addresses are wave-uniform (constant offsets after
// full unroll) -> s_load_dwordx16 into SGPRs; body is pure v_fmac.
// Reads its agg row (in d_out) fully before overwriting in place.
__global__ __launch_bounds__(128) void linear_kernel(
    const float* __restrict__ x, const float* __restrict__ WT,
    const float* __restrict__ b, const float* __restrict__ gamma,
    const float* __restrict__ beta, float* __restrict__ out, int N)
{
    int n = blockIdx.x * 128 + threadIdx.x;
    if (n >= N) return;

    float acc[D], h[D];
    #pragma unroll
    for (int o = 0; o < D; ++o) acc[o] = b[o];

    // pass 1: h = x row (float4 loads)
    const float4* xr = (const float4*)(x + (size_t)n * D);
    #pragma unroll
    for (int t = 0; t < 16; ++t) {
        float4 v = xr[t];
        h[4*t] = v.x; h[4*t+1] = v.y; h[4*t+2] = v.z; h[4*t+3] = v.w;
    }
    #pragma unroll
    for (int k = 0; k < D; ++k) {
        #pragma unroll
        for (int o = 0; o < D; ++o)
            acc[o] = fmaf(h[k], WT[k * 64 + o], acc[o]);
    }

    // pass 2: h = agg row (already mean'ed, lives in out)
    const float4* ar = (const float4*)(out + (size_t)n * D);
    #pragma unroll
    for (int t = 0; t < 16; ++t) {
        float4 v = ar[t];
        h[4*t] = v.x; h[4*t+1] = v.y; h[4*t+2] = v.z; h[4*t+3] = v.w;
    }
    #pragma unroll
    for (int k = 0; k < D; ++k) {
        #pragma unroll
        for (int o = 0; o < D; ++o)
            acc[o] = fmaf(h[k], WT[(D + k) * 64 + o], acc[o]);
    }

    // ReLU + LayerNorm (thread owns the row; no cross-lane reduce)
    float mu = 0.f;
    #pragma unroll
    for (int o = 0; o < D; ++o) { acc[o] = fmaxf(acc[o], 0.f); mu += acc[o]; }
    mu *= (1.0f / D);
    float var = 0.f;
    #pragma unroll
    for (int o = 0; o < D; ++o) { float d0 = acc[o] - mu; var += d0 * d0; }
    var *= (1.0f / D);
    float r = rsqrtf(var + LN_EPS);

    float4* orow = (float4*)(out + (size_t)n * D);
    #pragma unroll
    for (int t = 0; t < 16; ++t) {
        float4 v;
        v.x = (acc[4*t]   - mu) * r * gamma[4*t]   + beta[4*t];
        v.y = (acc[4*t+1] - mu) * r * gamma[4*t+1] + beta[4*t+1];
        v.z = (acc[4*t+2] - mu) * r * gamma[4*t+2] + beta[4*t+2];
        v.w = (acc[4*t+3] - mu) * r * gamma[4*t+3] + beta[4*t+3];
        orow[t] = v;
    }
}

extern "C" void kernel_launch(void* const* d_in, const int* in_sizes, int n_in,
                              void* d_out, int out_size, void* d_ws, size_t ws_size,
                              hipStream_t stream)
{
    const float* x     = (const float*)d_in[0];
    const int*   ei    = (const int*)d_in[1];
    const float* W     = (const float*)d_in[2];
    const float* b     = (const float*)d_in[3];
    const float* gamma = (const float*)d_in[4];
    const float* beta  = (const float*)d_in[5];

    int N = in_sizes[0] / D;       // 100000
    int E = in_sizes[1] / 2;       // 1600000
    int nb = (N + 255) / 256;      // 391 (must be <= 512)

    // ws layout (ints, 4B each)
    int* wsI      = (int*)d_ws;
    int* degi     = wsI;                 // N
    int* locExcl  = wsI + N;             // N
    int* bsum     = wsI + 2 * N;         // 512
    int* offsets  = wsI + 2 * N + 512;   // N
    int* cursor   = wsI + 3 * N + 512;   // N
    int* col      = wsI + 4 * N + 512;   // E
    float* WT     = (float*)(wsI + 4 * N + 512 + E);  // 8192 floats

    float* out = (float*)d_out;    // agg scratch, then final output (in place)

    hipMemsetAsync(degi, 0, (size_t)N * sizeof(int), stream);

    int eb = (E + 255) / 256;
    hist_kernel <<<eb, 256, 0, stream>>>(ei, degi, E);
    scan1_kernel<<<nb, 256, 0, stream>>>(degi, locExcl, bsum, N);
    scan2_kernel<<<1, 512, 0, stream>>>(bsum, nb);
    scan3_kernel<<<nb, 256, 0, stream>>>(locExcl, bsum, offsets, cursor, N);
    fill_kernel <<<eb, 256, 0, stream>>>(ei, cursor, col, E);
    wt_kernel   <<<32, 256, 0, stream>>>(W, WT);

    int gb = (N * 64 + 255) / 256;
    gather_kernel<<<gb, 256, 0, stream>>>(col, offsets, degi, x, out, N);

    int lb = (N + 127) / 128;
    linear_kernel<<<lb, 128, 0, stream>>>(x, WT, b, gamma, beta, out, N);
}

// Round 3
// 356.410 us; speedup vs baseline: 1.6445x; 1.1609x over previous
//
#include <hip/hip_runtime.h>

#define D 64
#define LN_EPS 1e-5f
#define FPASS 8

// ---------------- CSR build ----------------

__global__ __launch_bounds__(256) void hist_kernel(
    const int* __restrict__ ei, int* __restrict__ degi, int E)
{
    int e = blockIdx.x * 256 + threadIdx.x;
    if (e < E) atomicAdd(&degi[ei[e]], 1);
}

// per-block exclusive scan (Hillis-Steele in LDS), emits block sums
__global__ __launch_bounds__(256) void scan1_kernel(
    const int* __restrict__ degi, int* __restrict__ locExcl,
    int* __restrict__ bsum, int N)
{
    __shared__ int s[256];
    int tid = threadIdx.x;
    int i = blockIdx.x * 256 + tid;
    int v = (i < N) ? degi[i] : 0;
    s[tid] = v;
    __syncthreads();
    for (int off = 1; off < 256; off <<= 1) {
        int t = (tid >= off) ? s[tid - off] : 0;
        __syncthreads();
        s[tid] += t;
        __syncthreads();
    }
    if (i < N) locExcl[i] = s[tid] - v;
    if (tid == 255) bsum[blockIdx.x] = s[255];
}

__global__ __launch_bounds__(512) void scan2_kernel(int* __restrict__ bsum, int nb)
{
    __shared__ int s[512];
    int tid = threadIdx.x;
    int v = (tid < nb) ? bsum[tid] : 0;
    s[tid] = v;
    __syncthreads();
    for (int off = 1; off < 512; off <<= 1) {
        int t = (tid >= off) ? s[tid - off] : 0;
        __syncthreads();
        s[tid] += t;
        __syncthreads();
    }
    if (tid < nb) bsum[tid] = s[tid] - v;   // exclusive
}

__global__ __launch_bounds__(256) void scan3_kernel(
    const int* __restrict__ locExcl, const int* __restrict__ bsum,
    int* __restrict__ offsets, int* __restrict__ cursor, int N)
{
    int i = blockIdx.x * 256 + threadIdx.x;
    if (i < N) {
        int o = locExcl[i] + bsum[blockIdx.x];
        offsets[i] = o;
        cursor[i]  = o;
    }
}

// XCD-banded fill: pass = blockIdx.x & 7 -> all blocks of a pass land on one
// XCD (round-robin dispatch heuristic). Each pass owns a 1/8 node range, so
// its col window (~0.8 MB) + cursors (~50 KB) stay resident in that XCD's L2
// until the pass drains -> each 64B col line collects all its ~16 writes
// before ONE write-back, instead of 1 line per 4B store (was 106 MB writes).
__global__ __launch_bounds__(256) void fill_kernel(
    const int* __restrict__ ei, int* __restrict__ cursor,
    int* __restrict__ col, int E, int nodesPerPass)
{
    int p = blockIdx.x & (FPASS - 1);
    int c = blockIdx.x >> 3;
    int e = c * 256 + threadIdx.x;
    if (e >= E) return;
    int dst = ei[e];
    if (dst / nodesPerPass != p) return;
    int src = ei[E + e];
    int pos = atomicAdd(&cursor[dst], 1);
    col[pos] = src;
}

// W[64][128] row-major -> WT[128][64] so WT[k*64+o] = W[o*128+k]
__global__ __launch_bounds__(256) void wt_kernel(
    const float* __restrict__ W, float* __restrict__ WT)
{
    int t = blockIdx.x * 256 + threadIdx.x;   // 8192 total
    int k = t >> 6, o = t & 63;
    WT[t] = W[o * 128 + k];
}

// ---------------- gather aggregation: one wave per node ----------------
// 16 lanes per neighbor row, float4 per lane -> one load instr covers 4
// neighbor rows (1 KB/wave). Neighbor indices prefetched 64-wide, broadcast
// via per-lane-variable __shfl. Cross-subgroup reduce via shfl_xor(32,16).
__global__ __launch_bounds__(256) void gather_kernel(
    const int* __restrict__ col, const int* __restrict__ offsets,
    const int* __restrict__ degi, const float4* __restrict__ x4,
    float4* __restrict__ out4, int N)
{
    int w    = (blockIdx.x * 256 + threadIdx.x) >> 6;
    int lane = threadIdx.x & 63;
    if (w >= N) return;
    int base = offsets[w];
    int cnt  = degi[w];
    int g = lane >> 4;      // which of 4 concurrent neighbors
    int f = lane & 15;      // float4 slot within the 64-float row

    float sx = 0.f, sy = 0.f, sz = 0.f, sw = 0.f;
    for (int t = 0; t < cnt; t += 64) {
        int m = cnt - t; if (m > 64) m = 64;
        int idxreg = (lane < m) ? col[base + t + lane] : 0;
        for (int j = 0; j < m; j += 4) {
            int nb = __shfl(idxreg, j + g);
            if (j + g < m) {
                float4 v = x4[(size_t)nb * 16 + f];
                sx += v.x; sy += v.y; sz += v.z; sw += v.w;
            }
        }
    }
    sx += __shfl_xor(sx, 32); sy += __shfl_xor(sy, 32);
    sz += __shfl_xor(sz, 32); sw += __shfl_xor(sw, 32);
    sx += __shfl_xor(sx, 16); sy += __shfl_xor(sy, 16);
    sz += __shfl_xor(sz, 16); sw += __shfl_xor(sw, 16);

    if (lane < 16) {
        float inv = 1.0f / fmaxf((float)cnt, 1.0f);
        float4 r;
        r.x = sx * inv; r.y = sy * inv; r.z = sz * inv; r.w = sw * inv;
        out4[(size_t)w * 16 + f] = r;   // mean stored directly
    }
}

// ---------------- fused linear + ReLU + LayerNorm ----------------
// Thread-per-node. WT addresses are wave-uniform (constant offsets after
// full unroll) -> s_load into SGPRs; body is pure v_fmac.
__global__ __launch_bounds__(128) void linear_kernel(
    const float* __restrict__ x, const float* __restrict__ WT,
    const float* __restrict__ b, const float* __restrict__ gamma,
    const float* __restrict__ beta, float* __restrict__ out, int N)
{
    int n = blockIdx.x * 128 + threadIdx.x;
    if (n >= N) return;

    float acc[D], h[D];
    #pragma unroll
    for (int o = 0; o < D; ++o) acc[o] = b[o];

    const float4* xr = (const float4*)(x + (size_t)n * D);
    #pragma unroll
    for (int t = 0; t < 16; ++t) {
        float4 v = xr[t];
        h[4*t] = v.x; h[4*t+1] = v.y; h[4*t+2] = v.z; h[4*t+3] = v.w;
    }
    #pragma unroll
    for (int k = 0; k < D; ++k) {
        #pragma unroll
        for (int o = 0; o < D; ++o)
            acc[o] = fmaf(h[k], WT[k * 64 + o], acc[o]);
    }

    const float4* ar = (const float4*)(out + (size_t)n * D);
    #pragma unroll
    for (int t = 0; t < 16; ++t) {
        float4 v = ar[t];
        h[4*t] = v.x; h[4*t+1] = v.y; h[4*t+2] = v.z; h[4*t+3] = v.w;
    }
    #pragma unroll
    for (int k = 0; k < D; ++k) {
        #pragma unroll
        for (int o = 0; o < D; ++o)
            acc[o] = fmaf(h[k], WT[(D + k) * 64 + o], acc[o]);
    }

    float mu = 0.f;
    #pragma unroll
    for (int o = 0; o < D; ++o) { acc[o] = fmaxf(acc[o], 0.f); mu += acc[o]; }
    mu *= (1.0f / D);
    float var = 0.f;
    #pragma unroll
    for (int o = 0; o < D; ++o) { float d0 = acc[o] - mu; var += d0 * d0; }
    var *= (1.0f / D);
    float r = rsqrtf(var + LN_EPS);

    float4* orow = (float4*)(out + (size_t)n * D);
    #pragma unroll
    for (int t = 0; t < 16; ++t) {
        float4 v;
        v.x = (acc[4*t]   - mu) * r * gamma[4*t]   + beta[4*t];
        v.y = (acc[4*t+1] - mu) * r * gamma[4*t+1] + beta[4*t+1];
        v.z = (acc[4*t+2] - mu) * r * gamma[4*t+2] + beta[4*t+2];
        v.w = (acc[4*t+3] - mu) * r * gamma[4*t+3] + beta[4*t+3];
        orow[t] = v;
    }
}

extern "C" void kernel_launch(void* const* d_in, const int* in_sizes, int n_in,
                              void* d_out, int out_size, void* d_ws, size_t ws_size,
                              hipStream_t stream)
{
    const float* x     = (const float*)d_in[0];
    const int*   ei    = (const int*)d_in[1];
    const float* W     = (const float*)d_in[2];
    const float* b     = (const float*)d_in[3];
    const float* gamma = (const float*)d_in[4];
    const float* beta  = (const float*)d_in[5];

    int N = in_sizes[0] / D;       // 100000
    int E = in_sizes[1] / 2;       // 1600000
    int nb = (N + 255) / 256;      // 391 (must be <= 512)
    int nodesPerPass = (N + FPASS - 1) / FPASS;

    int* wsI      = (int*)d_ws;
    int* degi     = wsI;                 // N
    int* locExcl  = wsI + N;             // N
    int* bsum     = wsI + 2 * N;         // 512
    int* offsets  = wsI + 2 * N + 512;   // N
    int* cursor   = wsI + 3 * N + 512;   // N
    int* col      = wsI + 4 * N + 512;   // E
    float* WT     = (float*)(wsI + 4 * N + 512 + E);  // 8192 floats

    float* out = (float*)d_out;

    hipMemsetAsync(degi, 0, (size_t)N * sizeof(int), stream);

    int eb = (E + 255) / 256;
    hist_kernel <<<eb, 256, 0, stream>>>(ei, degi, E);
    scan1_kernel<<<nb, 256, 0, stream>>>(degi, locExcl, bsum, N);
    scan2_kernel<<<1, 512, 0, stream>>>(bsum, nb);
    scan3_kernel<<<nb, 256, 0, stream>>>(locExcl, bsum, offsets, cursor, N);
    fill_kernel <<<eb * FPASS, 256, 0, stream>>>(ei, cursor, col, E, nodesPerPass);
    wt_kernel   <<<32, 256, 0, stream>>>(W, WT);

    int gb = (N * 64 + 255) / 256;
    gather_kernel<<<gb, 256, 0, stream>>>(col, offsets, degi, (const float4*)x,
                                          (float4*)out, N);

    int lb = (N + 127) / 128;
    linear_kernel<<<lb, 128, 0, stream>>>(x, WT, b, gamma, beta, out, N);
}

// Round 4
// 350.697 us; speedup vs baseline: 1.6713x; 1.0163x over previous
//
#include <hip/hip_runtime.h>

#define D 64
#define LN_EPS 1e-5f
#define FPASS 8

// ---------------- CSR build ----------------

__global__ __launch_bounds__(256) void hist_kernel(
    const int* __restrict__ ei, int* __restrict__ degi, int E)
{
    int e = blockIdx.x * 256 + threadIdx.x;
    if (e < E) atomicAdd(&degi[ei[e]], 1);
}

// per-block exclusive scan (Hillis-Steele in LDS), emits block sums
__global__ __launch_bounds__(256) void scan1_kernel(
    const int* __restrict__ degi, int* __restrict__ locExcl,
    int* __restrict__ bsum, int N)
{
    __shared__ int s[256];
    int tid = threadIdx.x;
    int i = blockIdx.x * 256 + tid;
    int v = (i < N) ? degi[i] : 0;
    s[tid] = v;
    __syncthreads();
    for (int off = 1; off < 256; off <<= 1) {
        int t = (tid >= off) ? s[tid - off] : 0;
        __syncthreads();
        s[tid] += t;
        __syncthreads();
    }
    if (i < N) locExcl[i] = s[tid] - v;
    if (tid == 255) bsum[blockIdx.x] = s[255];
}

__global__ __launch_bounds__(512) void scan2_kernel(int* __restrict__ bsum, int nb)
{
    __shared__ int s[512];
    int tid = threadIdx.x;
    int v = (tid < nb) ? bsum[tid] : 0;
    s[tid] = v;
    __syncthreads();
    for (int off = 1; off < 512; off <<= 1) {
        int t = (tid >= off) ? s[tid - off] : 0;
        __syncthreads();
        s[tid] += t;
        __syncthreads();
    }
    if (tid < nb) bsum[tid] = s[tid] - v;   // exclusive
}

__global__ __launch_bounds__(256) void scan3_kernel(
    const int* __restrict__ locExcl, const int* __restrict__ bsum,
    int* __restrict__ offsets, int* __restrict__ cursor, int N)
{
    int i = blockIdx.x * 256 + threadIdx.x;
    if (i < N) {
        int o = locExcl[i] + bsum[blockIdx.x];
        offsets[i] = o;
        cursor[i]  = o;
    }
}

// XCD-banded fill (see R2/R3): pass = blockIdx.x & 7 keeps each node-range's
// col window resident in one XCD's L2 so lines accumulate writes.
__global__ __launch_bounds__(256) void fill_kernel(
    const int* __restrict__ ei, int* __restrict__ cursor,
    int* __restrict__ col, int E, int nodesPerPass)
{
    int p = blockIdx.x & (FPASS - 1);
    int c = blockIdx.x >> 3;
    int e = c * 256 + threadIdx.x;
    if (e >= E) return;
    int dst = ei[e];
    if (dst / nodesPerPass != p) return;
    int src = ei[E + e];
    int pos = atomicAdd(&cursor[dst], 1);
    col[pos] = src;
}

// W[64][128] row-major -> WT[128][64] so WT[k*64+o] = W[o*128+k]
__global__ __launch_bounds__(256) void wt_kernel(
    const float* __restrict__ W, float* __restrict__ WT)
{
    int t = blockIdx.x * 256 + threadIdx.x;   // 8192 total
    int k = t >> 6, o = t & 63;
    WT[t] = W[o * 128 + k];
}

// ---------------- gather aggregation: one wave per node ----------------
__global__ __launch_bounds__(256) void gather_kernel(
    const int* __restrict__ col, const int* __restrict__ offsets,
    const int* __restrict__ degi, const float4* __restrict__ x4,
    float4* __restrict__ out4, int N)
{
    int w    = (blockIdx.x * 256 + threadIdx.x) >> 6;
    int lane = threadIdx.x & 63;
    if (w >= N) return;
    int base = offsets[w];
    int cnt  = degi[w];
    int g = lane >> 4;      // which of 4 concurrent neighbors
    int f = lane & 15;      // float4 slot within the 64-float row

    float sx = 0.f, sy = 0.f, sz = 0.f, sw = 0.f;
    for (int t = 0; t < cnt; t += 64) {
        int m = cnt - t; if (m > 64) m = 64;
        int idxreg = (lane < m) ? col[base + t + lane] : 0;
        for (int j = 0; j < m; j += 4) {
            int nb = __shfl(idxreg, j + g);
            if (j + g < m) {
                float4 v = x4[(size_t)nb * 16 + f];
                sx += v.x; sy += v.y; sz += v.z; sw += v.w;
            }
        }
    }
    sx += __shfl_xor(sx, 32); sy += __shfl_xor(sy, 32);
    sz += __shfl_xor(sz, 32); sw += __shfl_xor(sw, 32);
    sx += __shfl_xor(sx, 16); sy += __shfl_xor(sy, 16);
    sz += __shfl_xor(sz, 16); sw += __shfl_xor(sw, 16);

    if (lane < 16) {
        float inv = 1.0f / fmaxf((float)cnt, 1.0f);
        float4 r;
        r.x = sx * inv; r.y = sy * inv; r.z = sz * inv; r.w = sw * inv;
        out4[(size_t)w * 16 + f] = r;   // mean stored directly
    }
}

// ---------------- fused linear + ReLU + LayerNorm ----------------
// Wave-per-8-nodes: lane o owns output o, acc[8] per lane. W (k-major) lives
// in LDS (bank = lane%32, 2-way conflict = free), amortized 8x across nodes.
// The h operand x[node*64+k] is wave-uniform (node forced scalar via
// readfirstlane) -> s_load + v_fmac with SGPR operand. LN = 64-lane shfl_xor
// butterfly. Reads its agg rows (in out) fully before overwriting in place.
__global__ __launch_bounds__(256) void linear_kernel(
    const float* __restrict__ x, const float* __restrict__ WT,
    const float* __restrict__ b, const float* __restrict__ gamma,
    const float* __restrict__ beta, float* __restrict__ out, int N)
{
    __shared__ float sWT[128 * 64];   // 32 KB
    for (int i = threadIdx.x; i < 128 * 64; i += 256) sWT[i] = WT[i];
    __syncthreads();

    int lane = threadIdx.x & 63;
    int wv = __builtin_amdgcn_readfirstlane(threadIdx.x >> 6);
    int nodeBase = blockIdx.x * 32 + wv * 8;
    if (nodeBase >= N) return;

    int nm[8];
    #pragma unroll
    for (int m = 0; m < 8; ++m) {
        int n = nodeBase + m;
        nm[m] = (n < N) ? n : (N - 1);   // clamp (harness N divides evenly)
    }

    float acc[8];
    float bo = b[lane];
    #pragma unroll
    for (int m = 0; m < 8; ++m) acc[m] = bo;

    // K part 1: h = x row
    #pragma unroll 4
    for (int k = 0; k < 64; ++k) {
        float w = sWT[k * 64 + lane];
        #pragma unroll
        for (int m = 0; m < 8; ++m)
            acc[m] = fmaf(x[(size_t)nm[m] * 64 + k], w, acc[m]);
    }
    // K part 2: h = agg row (mean already applied; lives in out)
    #pragma unroll 4
    for (int k = 0; k < 64; ++k) {
        float w = sWT[(64 + k) * 64 + lane];
        #pragma unroll
        for (int m = 0; m < 8; ++m)
            acc[m] = fmaf(out[(size_t)nm[m] * 64 + k], w, acc[m]);
    }

    float g  = gamma[lane];
    float be = beta[lane];
    #pragma unroll
    for (int m = 0; m < 8; ++m) {
        float v = fmaxf(acc[m], 0.f);
        float s = v, q = v * v;
        #pragma unroll
        for (int off = 32; off >= 1; off >>= 1) {
            s += __shfl_xor(s, off);
            q += __shfl_xor(q, off);
        }
        float mu  = s * (1.0f / 64.0f);
        float var = q * (1.0f / 64.0f) - mu * mu;
        float r = rsqrtf(var + LN_EPS);
        if (nodeBase + m < N)
            out[(size_t)(nodeBase + m) * 64 + lane] = (v - mu) * r * g + be;
    }
}

extern "C" void kernel_launch(void* const* d_in, const int* in_sizes, int n_in,
                              void* d_out, int out_size, void* d_ws, size_t ws_size,
                              hipStream_t stream)
{
    const float* x     = (const float*)d_in[0];
    const int*   ei    = (const int*)d_in[1];
    const float* W     = (const float*)d_in[2];
    const float* b     = (const float*)d_in[3];
    const float* gamma = (const float*)d_in[4];
    const float* beta  = (const float*)d_in[5];

    int N = in_sizes[0] / D;       // 100000
    int E = in_sizes[1] / 2;       // 1600000
    int nb = (N + 255) / 256;      // 391 (must be <= 512)
    int nodesPerPass = (N + FPASS - 1) / FPASS;

    int* wsI      = (int*)d_ws;
    int* degi     = wsI;                 // N
    int* locExcl  = wsI + N;             // N
    int* bsum     = wsI + 2 * N;         // 512
    int* offsets  = wsI + 2 * N + 512;   // N
    int* cursor   = wsI + 3 * N + 512;   // N
    int* col      = wsI + 4 * N + 512;   // E
    float* WT     = (float*)(wsI + 4 * N + 512 + E);  // 8192 floats

    float* out = (float*)d_out;

    hipMemsetAsync(degi, 0, (size_t)N * sizeof(int), stream);

    int eb = (E + 255) / 256;
    hist_kernel <<<eb, 256, 0, stream>>>(ei, degi, E);
    scan1_kernel<<<nb, 256, 0, stream>>>(degi, locExcl, bsum, N);
    scan2_kernel<<<1, 512, 0, stream>>>(bsum, nb);
    scan3_kernel<<<nb, 256, 0, stream>>>(locExcl, bsum, offsets, cursor, N);
    fill_kernel <<<eb * FPASS, 256, 0, stream>>>(ei, cursor, col, E, nodesPerPass);
    wt_kernel   <<<32, 256, 0, stream>>>(W, WT);

    int gb = (N * 64 + 255) / 256;
    gather_kernel<<<gb, 256, 0, stream>>>(col, offsets, degi, (const float4*)x,
                                          (float4*)out, N);

    int lb = (N + 31) / 32;   // 32 nodes per block (4 waves x 8)
    linear_kernel<<<lb, 256, 0, stream>>>(x, WT, b, gamma, beta, out, N);
}

// Round 5
// 300.707 us; speedup vs baseline: 1.9491x; 1.1662x over previous
//
#include <hip/hip_runtime.h>

#define D 64
#define LN_EPS 1e-5f
#define FPASS 8

typedef __attribute__((ext_vector_type(8))) short short8;
typedef __attribute__((ext_vector_type(4))) float v4f;

__device__ __forceinline__ unsigned short f2bf(float f) {
    union { float f; unsigned u; } v; v.f = f;
    unsigned r = (v.u + 0x7fffu + ((v.u >> 16) & 1u)) >> 16;   // RNE
    return (unsigned short)r;
}

// ---------------- CSR build ----------------

__global__ __launch_bounds__(256) void hist_kernel(
    const int* __restrict__ ei, int* __restrict__ degi, int E, int N)
{
    int e = blockIdx.x * 256 + threadIdx.x;
    if (e >= E) return;
    unsigned dst = (unsigned)ei[e];
    if (dst < (unsigned)N) atomicAdd(&degi[dst], 1);   // clamp: replay-safe
}

__global__ __launch_bounds__(256) void scan1_kernel(
    const int* __restrict__ degi, int* __restrict__ locExcl,
    int* __restrict__ bsum, int N)
{
    __shared__ int s[256];
    int tid = threadIdx.x;
    int i = blockIdx.x * 256 + tid;
    int v = (i < N) ? degi[i] : 0;
    s[tid] = v;
    __syncthreads();
    for (int off = 1; off < 256; off <<= 1) {
        int t = (tid >= off) ? s[tid - off] : 0;
        __syncthreads();
        s[tid] += t;
        __syncthreads();
    }
    if (i < N) locExcl[i] = s[tid] - v;
    if (tid == 255) bsum[blockIdx.x] = s[255];
}

__global__ __launch_bounds__(512) void scan2_kernel(int* __restrict__ bsum, int nb)
{
    __shared__ int s[512];
    int tid = threadIdx.x;
    int v = (tid < nb) ? bsum[tid] : 0;
    s[tid] = v;
    __syncthreads();
    for (int off = 1; off < 512; off <<= 1) {
        int t = (tid >= off) ? s[tid - off] : 0;
        __syncthreads();
        s[tid] += t;
        __syncthreads();
    }
    if (tid < nb) bsum[tid] = s[tid] - v;
}

__global__ __launch_bounds__(256) void scan3_kernel(
    const int* __restrict__ locExcl, const int* __restrict__ bsum,
    int* __restrict__ offsets, int* __restrict__ cursor, int N)
{
    int i = blockIdx.x * 256 + threadIdx.x;
    if (i < N) {
        int o = locExcl[i] + bsum[blockIdx.x];
        offsets[i] = o;
        cursor[i]  = o;
    }
}

// XCD-banded fill (R3 win): pass = blockIdx.x & 7 keeps each node-range's col
// window resident in one XCD's L2 so 64B lines accumulate their ~16 writes.
__global__ __launch_bounds__(256) void fill_kernel(
    const int* __restrict__ ei, int* __restrict__ cursor,
    int* __restrict__ col, int E, int nodesPerPass, int N)
{
    int p = blockIdx.x & (FPASS - 1);
    int c = blockIdx.x >> 3;
    int e = c * 256 + threadIdx.x;
    if (e >= E) return;
    unsigned dst = (unsigned)ei[e];
    if (dst >= (unsigned)N) return;          // clamp: replay-safe
    if ((int)dst / nodesPerPass != p) return;
    unsigned src = (unsigned)ei[E + e];
    if (src >= (unsigned)N) src = 0;         // clamp: replay-safe
    int pos = atomicAdd(&cursor[dst], 1);
    col[pos] = (int)src;
}

// W[64][128] row-major -> WTB bf16 in MFMA B-fragment order:
// frag (s,t), lane l, elem j  <-  B[k = s*32+(l>>4)*8+j][n = t*16+(l&15)]
// linear index i = ((s*4+t)*64 + l)*8 + j
__global__ __launch_bounds__(256) void wtb_kernel(
    const float* __restrict__ W, unsigned short* __restrict__ WTB)
{
    int i = blockIdx.x * 256 + threadIdx.x;   // 8192 total
    int j = i & 7;
    int l = (i >> 3) & 63;
    int st = i >> 9;                          // 0..15
    int s = st >> 2, t = st & 3;
    int o = t * 16 + (l & 15);
    int k = s * 32 + (l >> 4) * 8 + j;
    WTB[i] = f2bf(W[o * 128 + k]);
}

// ---------------- gather aggregation: one wave per node ----------------
// 16 lanes per neighbor row, float4/lane -> 4 neighbor rows per load instr.
// Output mean written as bf16 into the spent ei buffer (12.8 MB, exact fit).
__global__ __launch_bounds__(256) void gather_kernel(
    const int* __restrict__ col, const int* __restrict__ offsets,
    const int* __restrict__ degi, const float4* __restrict__ x4,
    unsigned short* __restrict__ aggb, int N)
{
    int w    = (blockIdx.x * 256 + threadIdx.x) >> 6;
    int lane = threadIdx.x & 63;
    if (w >= N) return;
    int base = offsets[w];
    int cnt  = degi[w];
    int g = lane >> 4;
    int f = lane & 15;

    float sx = 0.f, sy = 0.f, sz = 0.f, sw = 0.f;
    for (int t = 0; t < cnt; t += 64) {
        int m = cnt - t; if (m > 64) m = 64;
        int idxreg = (lane < m) ? col[base + t + lane] : 0;
        for (int j = 0; j < m; j += 4) {
            int nb = __shfl(idxreg, j + g);
            if (j + g < m) {
                float4 v = x4[(size_t)nb * 16 + f];
                sx += v.x; sy += v.y; sz += v.z; sw += v.w;
            }
        }
    }
    sx += __shfl_xor(sx, 32); sy += __shfl_xor(sy, 32);
    sz += __shfl_xor(sz, 32); sw += __shfl_xor(sw, 32);
    sx += __shfl_xor(sx, 16); sy += __shfl_xor(sy, 16);
    sz += __shfl_xor(sz, 16); sw += __shfl_xor(sw, 16);

    if (lane < 16) {
        float inv = 1.0f / fmaxf((float)cnt, 1.0f);
        ushort4 r4;
        r4.x = f2bf(sx * inv); r4.y = f2bf(sy * inv);
        r4.z = f2bf(sz * inv); r4.w = f2bf(sw * inv);
        *(ushort4*)(aggb + (size_t)w * 64 + f * 4) = r4;
    }
}

// ---------------- fused linear + ReLU + LayerNorm via bf16 MFMA ----------------
// Wave computes a 16-node x 64-out tile: 4 K-steps x 4 N-tiles of
// mfma_f32_16x16x32_bf16. A: lane holds A[m=lane&15][k=(lane>>4)*8+j]
// (x fp32 cvt'd in regs; agg read as bf16). B: prepacked frag-order WTB,
// one 16B coalesced load per frag. C layout: row=(lane>>4)*4+reg, col=lane&15.
// Epilogue: bias+ReLU, LN per node via shfl_xor(1,2,4,8) within the quad.
__global__ __launch_bounds__(256) void linear_kernel(
    const float* __restrict__ x, const unsigned short* __restrict__ aggb,
    const unsigned short* __restrict__ WTB, const float* __restrict__ b,
    const float* __restrict__ gamma, const float* __restrict__ beta,
    float* __restrict__ out, int N)
{
    int lane = threadIdx.x & 63;
    int wv   = threadIdx.x >> 6;
    int nb   = blockIdx.x * 64 + wv * 16;
    if (nb >= N) return;
    int c = lane & 15, q = lane >> 4;
    int nm = nb + c; if (nm >= N) nm = N - 1;

    // B fragments: 16 x 16B coalesced loads (L2-hot, shared by all waves)
    short8 bf[4][4];
    const short8* WB = (const short8*)WTB;
    #pragma unroll
    for (int s = 0; s < 4; ++s)
        #pragma unroll
        for (int t = 0; t < 4; ++t)
            bf[s][t] = WB[(s * 4 + t) * 64 + lane];

    v4f acc[4];
    #pragma unroll
    for (int t = 0; t < 4; ++t) acc[t] = 0.f;

    // K-steps 0,1: A from x (fp32 -> bf16 in regs)
    #pragma unroll
    for (int s = 0; s < 2; ++s) {
        const float4* xp = (const float4*)(x + (size_t)nm * 64 + s * 32 + q * 8);
        float4 u0 = xp[0], u1 = xp[1];
        short8 af;
        af[0] = (short)f2bf(u0.x); af[1] = (short)f2bf(u0.y);
        af[2] = (short)f2bf(u0.z); af[3] = (short)f2bf(u0.w);
        af[4] = (short)f2bf(u1.x); af[5] = (short)f2bf(u1.y);
        af[6] = (short)f2bf(u1.z); af[7] = (short)f2bf(u1.w);
        #pragma unroll
        for (int t = 0; t < 4; ++t)
            acc[t] = __builtin_amdgcn_mfma_f32_16x16x32_bf16(af, bf[s][t], acc[t], 0, 0, 0);
    }
    // K-steps 2,3: A from aggb (already bf16)
    #pragma unroll
    for (int s = 0; s < 2; ++s) {
        short8 af = *(const short8*)(aggb + (size_t)nm * 64 + s * 32 + q * 8);
        #pragma unroll
        for (int t = 0; t < 4; ++t)
            acc[t] = __builtin_amdgcn_mfma_f32_16x16x32_bf16(af, bf[2 + s][t], acc[t], 0, 0, 0);
    }

    // epilogue
    float bb[4], gg[4], be[4];
    #pragma unroll
    for (int t = 0; t < 4; ++t) {
        bb[t] = b[t * 16 + c];
        gg[t] = gamma[t * 16 + c];
        be[t] = beta[t * 16 + c];
    }

    #pragma unroll
    for (int r = 0; r < 4; ++r) {
        int node = nb + q * 4 + r;
        float v[4];
        float s0 = 0.f, q0 = 0.f;
        #pragma unroll
        for (int t = 0; t < 4; ++t) {
            float vv = acc[t][r] + bb[t];
            vv = fmaxf(vv, 0.f);
            v[t] = vv;
            s0 += vv; q0 += vv * vv;
        }
        #pragma unroll
        for (int off = 1; off <= 8; off <<= 1) {   // reduce within the 16-lane quad
            s0 += __shfl_xor(s0, off);
            q0 += __shfl_xor(q0, off);
        }
        float mu  = s0 * (1.0f / 64.0f);
        float var = q0 * (1.0f / 64.0f) - mu * mu;
        float rs  = rsqrtf(var + LN_EPS);
        if (node < N) {
            #pragma unroll
            for (int t = 0; t < 4; ++t)
                out[(size_t)node * 64 + t * 16 + c] = (v[t] - mu) * rs * gg[t] + be[t];
        }
    }
}

extern "C" void kernel_launch(void* const* d_in, const int* in_sizes, int n_in,
                              void* d_out, int out_size, void* d_ws, size_t ws_size,
                              hipStream_t stream)
{
    const float* x     = (const float*)d_in[0];
    const int*   ei    = (const int*)d_in[1];
    const float* W     = (const float*)d_in[2];
    const float* b     = (const float*)d_in[3];
    const float* gamma = (const float*)d_in[4];
    const float* beta  = (const float*)d_in[5];

    int N = in_sizes[0] / D;       // 100000
    int E = in_sizes[1] / 2;       // 1600000
    int nb = (N + 255) / 256;
    int nodesPerPass = (N + FPASS - 1) / FPASS;

    int* wsI      = (int*)d_ws;
    int* degi     = wsI;                 // N
    int* locExcl  = wsI + N;             // N
    int* bsum     = wsI + 2 * N;         // 512
    int* offsets  = wsI + 2 * N + 512;   // N
    int* cursor   = wsI + 3 * N + 512;   // N
    int* col      = wsI + 4 * N + 512;   // E
    unsigned short* WTB = (unsigned short*)(wsI + 4 * N + 512 + E);  // 8192 bf16

    // ei is dead after fill_kernel; reuse its 12.8 MB as bf16 agg (N*64*2B, exact fit)
    unsigned short* aggb = (unsigned short*)d_in[1];

    float* out = (float*)d_out;

    hipMemsetAsync(degi, 0, (size_t)N * sizeof(int), stream);

    int eb = (E + 255) / 256;
    hist_kernel <<<eb, 256, 0, stream>>>(ei, degi, E, N);
    scan1_kernel<<<nb, 256, 0, stream>>>(degi, locExcl, bsum, N);
    scan2_kernel<<<1, 512, 0, stream>>>(bsum, nb);
    scan3_kernel<<<nb, 256, 0, stream>>>(locExcl, bsum, offsets, cursor, N);
    fill_kernel <<<eb * FPASS, 256, 0, stream>>>(ei, cursor, col, E, nodesPerPass, N);
    wtb_kernel  <<<32, 256, 0, stream>>>(W, WTB);

    int gb = (N * 64 + 255) / 256;
    gather_kernel<<<gb, 256, 0, stream>>>(col, offsets, degi, (const float4*)x,
                                          aggb, N);

    int lb = (N + 63) / 64;   // 64 nodes per block (4 waves x 16)
    linear_kernel<<<lb, 256, 0, stream>>>(x, aggb, WTB, b, gamma, beta, out, N);
}

// Round 6
// 256.231 us; speedup vs baseline: 2.2874x; 1.1736x over previous
//
#include <hip/hip_runtime.h>

#define D 64
#define LN_EPS 1e-5f
#define BN 128          // nodes per bucket
#define LNB 7           // log2(BN)
#define BC 2544         // edge capacity per bucket (avg 2046 + 11 sigma)
#define MAXNB 1024      // cnt/gbase LDS arrays sized for NB <= 1024

typedef __attribute__((ext_vector_type(8))) short short8;
typedef __attribute__((ext_vector_type(4))) float v4f;

__device__ __forceinline__ unsigned short f2bf(float f) {
    union { float f; unsigned u; } v; v.f = f;
    unsigned r = (v.u + 0x7fffu + ((v.u >> 16) & 1u)) >> 16;   // RNE
    return (unsigned short)r;
}

// ---------------- bin_place: counting-bin edges by dst bucket ----------------
// pairs[bkt*BC + slot] = (dstLocal << 17) | src  (dl < 128, src < 2^17).
// Per-block LDS histogram -> one global reservation atomic per (block,bucket)
// -> contiguous per-block runs inside each bucket window (line-friendly).
// Block 0 additionally builds WTB (bf16 W in MFMA B-fragment order).
__global__ __launch_bounds__(256) void bin_place_kernel(
    const int* __restrict__ ei, int* __restrict__ cursor,
    int* __restrict__ pairs, const float* __restrict__ W,
    unsigned short* __restrict__ WTB, int E, int N, int NB)
{
    __shared__ int cnt[MAXNB];
    __shared__ int gbase[MAXNB];
    int t = threadIdx.x;

    if (blockIdx.x == 0) {
        // WTB: frag (s,tt), lane l, elem j <- W[o=tt*16+(l&15)][k=s*32+(l>>4)*8+j]
        for (int i = t; i < 8192; i += 256) {
            int j = i & 7;
            int l = (i >> 3) & 63;
            int st = i >> 9;
            int s = st >> 2, tt = st & 3;
            int o = tt * 16 + (l & 15);
            int k = s * 32 + (l >> 4) * 8 + j;
            WTB[i] = f2bf(W[o * 128 + k]);
        }
    }

    for (int i = t; i < NB; i += 256) cnt[i] = 0;
    __syncthreads();

    int dstA[16], srcA[16], rkA[16];
    long long ebase = (long long)blockIdx.x * 4096;
    #pragma unroll
    for (int i = 0; i < 16; ++i) {
        long long e = ebase + i * 256 + t;
        int dst = 0, src = 0, rk = -1;
        if (e < E) {
            dst = ei[e]; src = ei[E + e];
            if ((unsigned)dst < (unsigned)N) {
                rk = atomicAdd(&cnt[dst >> LNB], 1);
                if ((unsigned)src >= (unsigned)N) src = 0;
            }
        }
        dstA[i] = dst; srcA[i] = src; rkA[i] = rk;
    }
    __syncthreads();

    for (int i = t; i < NB; i += 256) {
        int c = cnt[i];
        gbase[i] = c ? atomicAdd(&cursor[i], c) : 0;
    }
    __syncthreads();

    #pragma unroll
    for (int i = 0; i < 16; ++i) {
        if (rkA[i] >= 0) {
            int bkt = dstA[i] >> LNB;
            int slot = gbase[bkt] + rkA[i];
            if (slot < BC)
                pairs[bkt * BC + slot] = ((dstA[i] & (BN - 1)) << 17) | srcA[i];
        }
    }
}

// ---------------- fused: local sort + gather-aggregate + MFMA linear+LN ----------------
// One workgroup per 128-node bucket. Phase 1: LDS counting sort of the
// bucket's pairs (gives local deg/offsets = CSR, no global col). Phase 2:
// wave-per-node gather of x rows (float4, 16 lanes/row, 4 rows per instr),
// mean written as bf16 into LDS (row stride 72 shorts = 144B: 16B-aligned,
// conflict-free for the b128 A-frag reads). Phase 3: R5's 16-node MFMA tile
// x2 per wave, agg A-frags from LDS, bias+ReLU+LN epilogue, store out.
__global__ __launch_bounds__(256) void fused_kernel(
    const int* __restrict__ pairs, const int* __restrict__ cursor,
    const float* __restrict__ x, const unsigned short* __restrict__ WTB,
    const float* __restrict__ b, const float* __restrict__ gamma,
    const float* __restrict__ beta, float* __restrict__ out, int N)
{
    __shared__ int srcS[BC];                  // 10.2 KB
    __shared__ unsigned short aggL[BN][72];   // 18.4 KB (pad 64->72)
    __shared__ int cnt[BN], off[BN], cur[BN]; // 1.5 KB

    int t = threadIdx.x;
    int bkt = blockIdx.x;
    int bsize = cursor[bkt]; if (bsize > BC) bsize = BC;
    const int* pb = pairs + bkt * BC;

    if (t < BN) cnt[t] = 0;
    __syncthreads();
    for (int i = t; i < bsize; i += 256) atomicAdd(&cnt[pb[i] >> 17], 1);
    __syncthreads();

    // exclusive scan cnt -> off (Hillis over 128)
    if (t < BN) off[t] = cnt[t];
    __syncthreads();
    for (int s = 1; s < BN; s <<= 1) {
        int v = (t < BN && t >= s) ? off[t - s] : 0;
        __syncthreads();
        if (t < BN) off[t] += v;
        __syncthreads();
    }
    if (t < BN) { int ex = off[t] - cnt[t]; off[t] = ex; cur[t] = ex; }
    __syncthreads();

    for (int i = t; i < bsize; i += 256) {
        int p = pb[i];
        int pos = atomicAdd(&cur[p >> 17], 1);
        srcS[pos] = p & 0x1FFFF;
    }
    __syncthreads();

    // ---- phase 2: gather-aggregate, 32 nodes per wave ----
    int lane = t & 63, wv = t >> 6;
    int g = lane >> 4, f = lane & 15;
    const float4* x4 = (const float4*)x;
    for (int u = 0; u < 32; ++u) {
        int ln = wv * 32 + u;
        int deg = cnt[ln], base = off[ln];
        float sx = 0.f, sy = 0.f, sz = 0.f, sw = 0.f;
        for (int j = 0; j < deg; j += 4) {
            int idx = j + g;
            if (idx < deg) {
                int src = srcS[base + idx];        // broadcast within group
                float4 v = x4[(size_t)src * 16 + f];
                sx += v.x; sy += v.y; sz += v.z; sw += v.w;
            }
        }
        sx += __shfl_xor(sx, 32); sy += __shfl_xor(sy, 32);
        sz += __shfl_xor(sz, 32); sw += __shfl_xor(sw, 32);
        sx += __shfl_xor(sx, 16); sy += __shfl_xor(sy, 16);
        sz += __shfl_xor(sz, 16); sw += __shfl_xor(sw, 16);
        if (lane < 16) {
            float inv = 1.0f / fmaxf((float)deg, 1.0f);
            ushort4 r4;
            r4.x = f2bf(sx * inv); r4.y = f2bf(sy * inv);
            r4.z = f2bf(sz * inv); r4.w = f2bf(sw * inv);
            *(ushort4*)&aggL[ln][f * 4] = r4;
        }
    }
    __syncthreads();

    // ---- phase 3: MFMA linear + ReLU + LN ----
    short8 bf[4][4];
    const short8* WB = (const short8*)WTB;
    #pragma unroll
    for (int s = 0; s < 4; ++s)
        #pragma unroll
        for (int tt = 0; tt < 4; ++tt)
            bf[s][tt] = WB[(s * 4 + tt) * 64 + lane];

    int c = lane & 15, q = lane >> 4;
    float bb[4], gg[4], be[4];
    #pragma unroll
    for (int tt = 0; tt < 4; ++tt) {
        bb[tt] = b[tt * 16 + c];
        gg[tt] = gamma[tt * 16 + c];
        be[tt] = beta[tt * 16 + c];
    }

    for (int it = 0; it < 2; ++it) {
        int nt = bkt * BN + it * 64 + wv * 16;     // wave tile base node
        if (nt >= N) break;                        // wave-uniform
        int nm = nt + c; if (nm >= N) nm = N - 1;

        v4f acc[4];
        #pragma unroll
        for (int tt = 0; tt < 4; ++tt) acc[tt] = 0.f;

        // K-steps 0,1: A from x (fp32 -> bf16 in regs)
        #pragma unroll
        for (int s = 0; s < 2; ++s) {
            const float4* xp = (const float4*)(x + (size_t)nm * 64 + s * 32 + q * 8);
            float4 u0 = xp[0], u1 = xp[1];
            short8 af;
            af[0] = (short)f2bf(u0.x); af[1] = (short)f2bf(u0.y);
            af[2] = (short)f2bf(u0.z); af[3] = (short)f2bf(u0.w);
            af[4] = (short)f2bf(u1.x); af[5] = (short)f2bf(u1.y);
            af[6] = (short)f2bf(u1.z); af[7] = (short)f2bf(u1.w);
            #pragma unroll
            for (int tt = 0; tt < 4; ++tt)
                acc[tt] = __builtin_amdgcn_mfma_f32_16x16x32_bf16(af, bf[s][tt], acc[tt], 0, 0, 0);
        }
        // K-steps 2,3: A from aggL (bf16, 16B-aligned rows)
        int lnA = it * 64 + wv * 16 + c;
        #pragma unroll
        for (int s = 0; s < 2; ++s) {
            short8 af = *(const short8*)&aggL[lnA][s * 32 + q * 8];
            #pragma unroll
            for (int tt = 0; tt < 4; ++tt)
                acc[tt] = __builtin_amdgcn_mfma_f32_16x16x32_bf16(af, bf[2 + s][tt], acc[tt], 0, 0, 0);
        }

        // epilogue: bias + ReLU + LN per node row
        #pragma unroll
        for (int r = 0; r < 4; ++r) {
            int node = nt + q * 4 + r;
            float v[4];
            float s0 = 0.f, q0 = 0.f;
            #pragma unroll
            for (int tt = 0; tt < 4; ++tt) {
                float vv = acc[tt][r] + bb[tt];
                vv = fmaxf(vv, 0.f);
                v[tt] = vv;
                s0 += vv; q0 += vv * vv;
            }
            #pragma unroll
            for (int o = 1; o <= 8; o <<= 1) {
                s0 += __shfl_xor(s0, o);
                q0 += __shfl_xor(q0, o);
            }
            float mu  = s0 * (1.0f / 64.0f);
            float var = q0 * (1.0f / 64.0f) - mu * mu;
            float rs  = rsqrtf(var + LN_EPS);
            if (node < N) {
                #pragma unroll
                for (int tt = 0; tt < 4; ++tt)
                    out[(size_t)node * 64 + tt * 16 + c] = (v[tt] - mu) * rs * gg[tt] + be[tt];
            }
        }
    }
}

extern "C" void kernel_launch(void* const* d_in, const int* in_sizes, int n_in,
                              void* d_out, int out_size, void* d_ws, size_t ws_size,
                              hipStream_t stream)
{
    const float* x     = (const float*)d_in[0];
    const int*   ei    = (const int*)d_in[1];
    const float* W     = (const float*)d_in[2];
    const float* b     = (const float*)d_in[3];
    const float* gamma = (const float*)d_in[4];
    const float* beta  = (const float*)d_in[5];

    int N = in_sizes[0] / D;       // 100000
    int E = in_sizes[1] / 2;       // 1600000
    int NB = (N + BN - 1) / BN;    // 782 (<= MAXNB)

    // ws layout (ints): cursor[NB] | WTB (8192 bf16 = 4096 ints) | pairs[NB*BC]
    int* wsI = (int*)d_ws;
    int* cursor = wsI;
    unsigned short* WTB = (unsigned short*)(wsI + NB);
    int* pairs = wsI + NB + 4096;

    float* out = (float*)d_out;

    hipMemsetAsync(cursor, 0, (size_t)NB * sizeof(int), stream);

    int pblocks = (E + 4095) / 4096;
    bin_place_kernel<<<pblocks, 256, 0, stream>>>(ei, cursor, pairs, W, WTB, E, N, NB);

    fused_kernel<<<NB, 256, 0, stream>>>(pairs, cursor, x, WTB, b, gamma, beta, out, N);
}